// Round 2
// baseline (12.727 us; speedup 1.0000x reference)
//
#include <hip/hip_runtime.h>

// GeneratorLoss: out = sum_{b,s} log(clip(pred[b,s,x[b,s]], 1e-20, 1)) * rewards[b,s]
// pred: (4, 2048, 50257) fp32; x: (4,2048) int; rewards: (4,2048) fp32; out: scalar fp32.
// The one-hot/log over the vocab reduces to a gather: 8192 scattered fp32 loads.
// Round 2: spread the divergent gather over 128 CUs (128 blocks x 1 wave), so
// per-CU address-processing (~64 cache-line requests/instr, ~1/cycle) is ~64
// cycles instead of ~8192. Combine with one atomicAdd per block; d_out is
// zeroed first via hipMemsetAsync (graph-capture safe).

#define BN 4
#define SN 2048
#define VN 50257
#define NTOK (BN * SN)   // 8192
#define BLOCKS (NTOK / 64)

__global__ __launch_bounds__(64) void generator_loss_kernel(
    const float* __restrict__ pred,
    const int* __restrict__ x,
    const float* __restrict__ rewards,
    float* __restrict__ out) {
    const int i = blockIdx.x * 64 + threadIdx.x;

    int t = x[i];
    float r = rewards[i];
    float p = pred[(size_t)i * VN + (size_t)t];
    p = fminf(fmaxf(p, 1e-20f), 1.0f);
    float v = __logf(p) * r;

    // 64-lane wave butterfly reduce
    #pragma unroll
    for (int off = 32; off > 0; off >>= 1)
        v += __shfl_down(v, off, 64);

    if (threadIdx.x == 0)
        atomicAdd(out, v);
}

extern "C" void kernel_launch(void* const* d_in, const int* in_sizes, int n_in,
                              void* d_out, int out_size, void* d_ws, size_t ws_size,
                              hipStream_t stream) {
    const float* pred    = (const float*)d_in[0];
    const int*   x       = (const int*)d_in[1];
    const float* rewards = (const float*)d_in[2];
    float* out = (float*)d_out;

    hipMemsetAsync(out, 0, sizeof(float), stream);
    generator_loss_kernel<<<BLOCKS, 64, 0, stream>>>(pred, x, rewards, out);
}

// Round 3
// 10.618 us; speedup vs baseline: 1.1986x; 1.1986x over previous
//
#include <hip/hip_runtime.h>

// GeneratorLoss: out = sum_{b,s} log(clip(pred[b,s,x[b,s]], 1e-20, 1)) * rewards[b,s]
// pred: (4, 2048, 50257) fp32; x: (4,2048) int; rewards: (4,2048) fp32; out: scalar.
//
// The one-hot+log+sum over vocab reduces to a gather of 8192 scattered fp32s.
// Round-2 post-mortem showed duration = fixed replay floor (~10 us) + ~2 us per
// dispatch; kernel exec is ~1 us. So: ONE dispatch, ONE block (plain final
// store, no memset/atomics needed), and explicit 8-deep MLP per thread so the
// two dependent HBM round trips (x -> pred) overlap maximally across 16 waves.

#define VN 50257
#define NTOK 8192      // 4 * 2048
#define NT 1024
#define PT (NTOK / NT) // 8 tokens per thread

__global__ __launch_bounds__(1024) void generator_loss_kernel(
    const float* __restrict__ pred,
    const int* __restrict__ x,
    const float* __restrict__ rewards,
    float* __restrict__ out) {
    const int tid = threadIdx.x;

    // Phase 1: coalesced index/reward loads (all independent).
    int   t[PT];
    float r[PT];
    #pragma unroll
    for (int j = 0; j < PT; ++j) {
        t[j] = x[tid + j * NT];
        r[j] = rewards[tid + j * NT];
    }

    // Phase 2: 8 independent divergent gathers in flight per thread.
    float p[PT];
    #pragma unroll
    for (int j = 0; j < PT; ++j) {
        size_t i = (size_t)(tid + j * NT);
        p[j] = pred[i * VN + (size_t)t[j]];
    }

    // Phase 3: math + accumulate.
    float local = 0.0f;
    #pragma unroll
    for (int j = 0; j < PT; ++j) {
        float q = fminf(fmaxf(p[j], 1e-20f), 1.0f);
        local += __logf(q) * r[j];
    }

    // Wave butterfly reduce (64 lanes).
    #pragma unroll
    for (int off = 32; off > 0; off >>= 1)
        local += __shfl_down(local, off, 64);

    __shared__ float wave_sums[16];
    const int wave = tid >> 6;
    if ((tid & 63) == 0) wave_sums[wave] = local;
    __syncthreads();

    if (wave == 0) {
        float v = (tid < 16) ? wave_sums[tid] : 0.0f;
        #pragma unroll
        for (int off = 8; off > 0; off >>= 1)
            v += __shfl_down(v, off, 64);
        if (tid == 0) out[0] = v;
    }
}

extern "C" void kernel_launch(void* const* d_in, const int* in_sizes, int n_in,
                              void* d_out, int out_size, void* d_ws, size_t ws_size,
                              hipStream_t stream) {
    const float* pred    = (const float*)d_in[0];
    const int*   x       = (const int*)d_in[1];
    const float* rewards = (const float*)d_in[2];
    float* out = (float*)d_out;

    generator_loss_kernel<<<1, NT, 0, stream>>>(pred, x, rewards, out);
}